// Round 1
// baseline (273.587 us; speedup 1.0000x reference)
//
#include <hip/hip_runtime.h>
#include <hip/hip_bf16.h>

// Problem constants (from reference): B=32, L=8192, C=128, K=7, F=128
#define BATCH 32
#define LEN   8192
#define CDIM  128
#define TAPS  7
#define FDIM  128
#define LOUT  (LEN - TAPS + 1)   // 8186
#define BM    256                // output rows per block (was 128)
#define XROWS (BM + TAPS - 1)    // 262 rows of x per block
#define NCHUNK (TAPS * 2)        // 14 half-tap W chunks (F128 x C64 = 16 KB each)
#define NBUF  3                  // triple buffer -> prefetch distance 2, counted vmcnt

typedef __attribute__((ext_vector_type(8)))  short bf16x8;
typedef __attribute__((ext_vector_type(16))) float f32x16;

static __device__ __forceinline__ unsigned short bf16_rne(float f) {
    unsigned u = __float_as_uint(f);
    u += 0x7FFFu + ((u >> 16) & 1u);
    return (unsigned short)(u >> 16);
}
static __device__ __forceinline__ unsigned pack2(float a, float b) {
    return (unsigned)bf16_rne(a) | ((unsigned)bf16_rne(b) << 16);
}

// Pre-convert kernel W fp32 [K][C][F] -> bf16 transposed [K][F][C] in workspace.
__global__ void wconv_kernel(const float* __restrict__ w, ushort* __restrict__ wt) {
    int idx = blockIdx.x * 256 + threadIdx.x;         // 7*128*128 = 448*256 exactly
    int k = idx >> 14;
    int rem = idx & 16383;
    int f = rem >> 7;
    int c = rem & 127;
    wt[idx] = bf16_rne(w[(k << 14) + (c << 7) + f]);
}

// Main fused conv-as-GEMM kernel.
// Block: 512 threads (8 waves as 4x2). Tile: 256 output rows x 128 F.
// Xs: full X window in LDS (bf16, swizzled), loaded once (67 KB).
// Ws: TRIPLE-buffered 16 KB half-tap chunks via global_load_lds, prefetch
// distance 2. Steady-state barriers wait s_waitcnt vmcnt(2) -- the newest
// stage's 2 loads stay in flight ACROSS the barrier (T3+T4): no vmcnt(0)
// drain in the main loop. LDS total 116,224 B -> 1 block/CU, 8 waves/CU.
__global__ __launch_bounds__(512, 2)
void conv_gemm_kernel(const float* __restrict__ x, const ushort* __restrict__ wt,
                      float* __restrict__ out) {
    __shared__ __align__(16) ushort Xs[XROWS * CDIM];      // 67,072 B
    __shared__ __align__(16) ushort Ws[NBUF][FDIM * 64];   // 3 x 16,384 B

    const int tid  = threadIdx.x;
    const int lane = tid & 63;
    const int wid  = tid >> 6;       // 0..7
    const int wm   = wid >> 1;       // wave row (0..3) -> 64 rows each
    const int wn   = wid & 1;        // wave col (0..1) -> 64 f each
    const int l31  = lane & 31;
    const int l5   = lane >> 5;

    const int bid  = blockIdx.x;
    const int b    = bid >> 5;       // 32 row-tiles per batch
    const int i0   = (bid & 31) * BM;

    const float* xb = x + (size_t)b * LEN * CDIM;

    // ---- W chunk staging: async direct-to-LDS, swizzled (slot j' holds src j'^(f&7)) ----
    // Chunk idx: tap t = idx>>1, C-half h = idx&1. 1024 16B slots; 2 per thread.
    auto stage_w = [&](int idx, ushort* wbuf) {
        const ushort* wsrc = wt + (idx >> 1) * (FDIM * CDIM) + (idx & 1) * 64;
        #pragma unroll
        for (int it = 0; it < 2; ++it) {
            int s  = it * 512 + tid;            // slot this lane fills
            int f  = s >> 3;
            int jp = s & 7;
            int j  = jp ^ (f & 7);              // source 16B chunk within the half-row
            const ushort* g = wsrc + f * CDIM + j * 8;
            // wave-uniform LDS base (tid & 448 == wid*64); HW adds lane*16
            ushort* l = &wbuf[(it * 512 + (tid & 448)) * 8];
            __builtin_amdgcn_global_load_lds(
                (const __attribute__((address_space(1))) void*)g,
                (__attribute__((address_space(3))) void*)l, 16, 0, 0);
        }
    };

    stage_w(0, Ws[0]);   // prefetch chunk 0 (L2-hot after wconv)

    // ---- Stage X window: fp32 global -> bf16 LDS, swizzled (col ^= row&15) ----
    #pragma unroll
    for (int it = 0; it < 9; ++it) {
        int q = it * 512 + tid;
        if (q < XROWS * 16) {
            int r   = q >> 4;
            int col = q & 15;
            int gi  = i0 + r;
            float4 v0, v1;
            if (gi < LEN) {
                const float4* p = (const float4*)(xb + (size_t)gi * CDIM + col * 8);
                v0 = p[0]; v1 = p[1];
            } else {
                v0 = make_float4(0.f, 0.f, 0.f, 0.f);
                v1 = v0;
            }
            int scol = col ^ (r & 15);
            uint4 pk;
            pk.x = pack2(v0.x, v0.y);
            pk.y = pack2(v0.z, v0.w);
            pk.z = pack2(v1.x, v1.y);
            pk.w = pack2(v1.z, v1.w);
            *(uint4*)&Xs[r * CDIM + scol * 8] = pk;
        }
    }

    stage_w(1, Ws[1]);   // second chunk in flight

    // Chunk 0 landed (vmcnt FIFO: only the 2 newest -- stage 1's -- may fly),
    // X ds_writes drained, then workgroup barrier.
    asm volatile("s_waitcnt vmcnt(2) lgkmcnt(0)" ::: "memory");
    __builtin_amdgcn_s_barrier();

    f32x16 acc[2][2] = {};

    const int f0 = (wn << 6) + l31;
    const int f1 = f0 + 32;
    const int swz = l31 & 7;         // == f0&7 == f1&7

    #pragma unroll
    for (int idx = 0; idx < NCHUNK; ++idx) {
        // Prefetch distance 2 into the third buffer. buf[(idx+2)%3] was last
        // read in iter idx-1, whose trailing lgkmcnt(0)+barrier fences it.
        if (idx + 2 < NCHUNK) stage_w(idx + 2, Ws[(idx + 2) % NBUF]);

        const int t = idx >> 1;
        const int h = idx & 1;
        const ushort* wb = Ws[idx % NBUF];
        const int r0 = (wm << 6) + l31 + t;
        const int r1 = r0 + 32;

        __builtin_amdgcn_s_setprio(1);
        #pragma unroll
        for (int kk = 0; kk < 4; ++kk) {
            int jl = kk * 2 + l5;            // 0..7 within the C-half
            int jg = h * 8 + jl;             // 0..15 within the full row (for Xs)
            bf16x8 a0 = *(const bf16x8*)&Xs[r0 * CDIM + ((jg ^ (r0 & 15)) << 3)];
            bf16x8 a1 = *(const bf16x8*)&Xs[r1 * CDIM + ((jg ^ (r1 & 15)) << 3)];
            bf16x8 b0 = *(const bf16x8*)&wb[f0 * 64 + ((jl ^ swz) << 3)];
            bf16x8 b1 = *(const bf16x8*)&wb[f1 * 64 + ((jl ^ swz) << 3)];
            acc[0][0] = __builtin_amdgcn_mfma_f32_32x32x16_bf16(a0, b0, acc[0][0], 0, 0, 0);
            acc[0][1] = __builtin_amdgcn_mfma_f32_32x32x16_bf16(a0, b1, acc[0][1], 0, 0, 0);
            acc[1][0] = __builtin_amdgcn_mfma_f32_32x32x16_bf16(a1, b0, acc[1][0], 0, 0, 0);
            acc[1][1] = __builtin_amdgcn_mfma_f32_32x32x16_bf16(a1, b1, acc[1][1], 0, 0, 0);
        }
        __builtin_amdgcn_s_setprio(0);

        // End-of-phase sync. Steady state: COUNTED vmcnt(2) -- guarantees
        // stage(idx+1) (older) landed while stage(idx+2)'s 2 loads remain in
        // flight across the barrier. Only the last prefetched chunk needs a
        // full drain; the final iteration needs no barrier at all.
        if (idx + 2 < NCHUNK) {
            asm volatile("s_waitcnt vmcnt(2) lgkmcnt(0)" ::: "memory");
            __builtin_amdgcn_s_barrier();
        } else if (idx + 1 < NCHUNK) {
            asm volatile("s_waitcnt vmcnt(0) lgkmcnt(0)" ::: "memory");
            __builtin_amdgcn_s_barrier();
        }
    }

    // ---- Epilogue: C/D layout col=lane&31, row=(reg&3)+8*(reg>>2)+4*(lane>>5) ----
    float* ob = out + (size_t)b * LOUT * FDIM;
    #pragma unroll
    for (int fm = 0; fm < 2; ++fm) {
        #pragma unroll
        for (int fn = 0; fn < 2; ++fn) {
            #pragma unroll
            for (int r = 0; r < 16; ++r) {
                int row = (wm << 6) + (fm << 5) + (r & 3) + ((r >> 2) << 3) + (l5 << 2);
                int i = i0 + row;
                if (i < LOUT) {
                    ob[(size_t)i * FDIM + (wn << 6) + (fn << 5) + l31] = acc[fm][fn][r];
                }
            }
        }
    }
}

extern "C" void kernel_launch(void* const* d_in, const int* in_sizes, int n_in,
                              void* d_out, int out_size, void* d_ws, size_t ws_size,
                              hipStream_t stream) {
    const float* x = (const float*)d_in[0];   // [32, 8192, 128, 1] fp32
    const float* w = (const float*)d_in[1];   // [7, 128, 128] fp32
    float* out = (float*)d_out;               // [32, 8186, 128, 1] fp32
    ushort* wt = (ushort*)d_ws;               // 7*128*128 bf16 = 229,376 B scratch

    wconv_kernel<<<448, 256, 0, stream>>>(w, wt);
    conv_gemm_kernel<<<BATCH * 32, 512, 0, stream>>>(x, wt, out);
}

// Round 2
// 265.081 us; speedup vs baseline: 1.0321x; 1.0321x over previous
//
#include <hip/hip_runtime.h>
#include <hip/hip_bf16.h>

// Problem constants (from reference): B=32, L=8192, C=128, K=7, F=128
#define BATCH 32
#define LEN   8192
#define CDIM  128
#define TAPS  7
#define FDIM  128
#define LOUT  (LEN - TAPS + 1)   // 8186
#define BM    128                // output rows per block
#define XROWS (BM + TAPS - 1)    // 134 rows of x per block
#define NCHUNK (TAPS * 2)        // 14 (tap, C-half) combinations

typedef __attribute__((ext_vector_type(8)))  short bf16x8;
typedef __attribute__((ext_vector_type(16))) float f32x16;

static __device__ __forceinline__ unsigned short bf16_rne(float f) {
    unsigned u = __float_as_uint(f);
    u += 0x7FFFu + ((u >> 16) & 1u);
    return (unsigned short)(u >> 16);
}
static __device__ __forceinline__ unsigned pack2(float a, float b) {
    return (unsigned)bf16_rne(a) | ((unsigned)bf16_rne(b) << 16);
}

// Pre-convert W fp32 [K][C][F] -> bf16 in MFMA-FRAGMENT-MAJOR order:
// wt[t][h][kk][l5][f][e], e=0..7, where c = h*64 + kk*16 + l5*8 + e.
// A B-fragment global load in the main kernel is then a perfectly coalesced
// contiguous 512 B per 32-lane half (lane l31 -> consecutive f).
__global__ void wconv_kernel(const float* __restrict__ w, ushort* __restrict__ wt) {
    int i = blockIdx.x * 256 + threadIdx.x;   // 7*2*4*2*128*8 = 114688 = 448*256
    int e  = i & 7;
    int f  = (i >> 3) & 127;
    int l5 = (i >> 10) & 1;
    int kk = (i >> 11) & 3;
    int h  = (i >> 13) & 1;
    int t  = i >> 14;
    int c  = h * 64 + kk * 16 + l5 * 8 + e;
    wt[i] = bf16_rne(w[(t << 14) + (c << 7) + f]);
}

// Main fused conv-as-GEMM kernel.
// Block: 256 threads (4 waves as 2x2), tile 128 rows x 128 F, wave = 64x64.
// X window staged once in LDS (bf16, swizzled, 34,304 B) -> 4 blocks/CU ->
// 16 waves/CU (2x round 0/1's occupancy, which was the measured invariant
// pinning both at 121 us). W is NOT staged: B-fragments load directly from
// the fragment-major wt[] (229 KB, L2-resident), fully coalesced. The main
// loop has ZERO barriers and 4 independent acc chains -> maximal wave-level
// and instruction-level latency hiding.
__global__ __launch_bounds__(256, 4)
void conv_gemm_kernel(const float* __restrict__ x, const ushort* __restrict__ wt,
                      float* __restrict__ out) {
    __shared__ __align__(16) ushort Xs[XROWS * CDIM];      // 34,304 B (X only)

    const int tid  = threadIdx.x;
    const int lane = tid & 63;
    const int wid  = tid >> 6;       // 0..3
    const int wm   = wid >> 1;       // wave row (0..1) -> 64 rows
    const int wn   = wid & 1;        // wave col (0..1) -> 64 f
    const int l31  = lane & 31;
    const int l5   = lane >> 5;

    const int bid  = blockIdx.x;
    const int b    = bid >> 6;       // 64 row-tiles per batch
    const int i0   = (bid & 63) * BM;

    const float* xb = x + (size_t)b * LEN * CDIM;

    // ---- Stage X window: fp32 global -> bf16 LDS, swizzled (col ^= row&15) ----
    #pragma unroll
    for (int it = 0; it < 9; ++it) {
        int q = it * 256 + tid;
        if (q < XROWS * 16) {
            int r   = q >> 4;
            int col = q & 15;
            int gi  = i0 + r;
            float4 v0, v1;
            if (gi < LEN) {
                const float4* p = (const float4*)(xb + (size_t)gi * CDIM + col * 8);
                v0 = p[0]; v1 = p[1];
            } else {
                v0 = make_float4(0.f, 0.f, 0.f, 0.f);
                v1 = v0;
            }
            int scol = col ^ (r & 15);
            uint4 pk;
            pk.x = pack2(v0.x, v0.y);
            pk.y = pack2(v0.z, v0.w);
            pk.z = pack2(v1.x, v1.y);
            pk.w = pack2(v1.z, v1.w);
            *(uint4*)&Xs[r * CDIM + scol * 8] = pk;
        }
    }
    __syncthreads();                 // the ONLY barrier

    f32x16 acc[2][2] = {};

    const int f0 = (wn << 6) + l31;

    // Per-lane W fragment base: wt + idx*8192 + kk*2048 + l5*1024 + f0*8
    const ushort* wp = wt + (l5 << 10) + (f0 << 3);

    #pragma unroll
    for (int idx = 0; idx < NCHUNK; ++idx) {
        const int t = idx >> 1;
        const int h = idx & 1;
        const int r0 = (wm << 6) + l31 + t;
        const int r1 = r0 + 32;
        const ushort* wpi = wp + idx * 8192;

        #pragma unroll
        for (int kk = 0; kk < 4; ++kk) {
            int jl = kk * 2 + l5;            // 0..7 within the C-half
            int jg = h * 8 + jl;             // 0..15 within the full row (for Xs)
            bf16x8 a0 = *(const bf16x8*)&Xs[r0 * CDIM + ((jg ^ (r0 & 15)) << 3)];
            bf16x8 a1 = *(const bf16x8*)&Xs[r1 * CDIM + ((jg ^ (r1 & 15)) << 3)];
            bf16x8 b0 = *(const bf16x8*)&wpi[kk * 2048];
            bf16x8 b1 = *(const bf16x8*)&wpi[kk * 2048 + 256];   // f0+32
            acc[0][0] = __builtin_amdgcn_mfma_f32_32x32x16_bf16(a0, b0, acc[0][0], 0, 0, 0);
            acc[0][1] = __builtin_amdgcn_mfma_f32_32x32x16_bf16(a0, b1, acc[0][1], 0, 0, 0);
            acc[1][0] = __builtin_amdgcn_mfma_f32_32x32x16_bf16(a1, b0, acc[1][0], 0, 0, 0);
            acc[1][1] = __builtin_amdgcn_mfma_f32_32x32x16_bf16(a1, b1, acc[1][1], 0, 0, 0);
        }
    }

    // ---- Epilogue: C/D layout col=lane&31, row=(reg&3)+8*(reg>>2)+4*(lane>>5) ----
    float* ob = out + (size_t)b * LOUT * FDIM;
    #pragma unroll
    for (int fm = 0; fm < 2; ++fm) {
        #pragma unroll
        for (int fn = 0; fn < 2; ++fn) {
            #pragma unroll
            for (int r = 0; r < 16; ++r) {
                int row = (wm << 6) + (fm << 5) + (r & 3) + ((r >> 2) << 3) + (l5 << 2);
                int i = i0 + row;
                if (i < LOUT) {
                    ob[(size_t)i * FDIM + (wn << 6) + (fn << 5) + l31] = acc[fm][fn][r];
                }
            }
        }
    }
}

extern "C" void kernel_launch(void* const* d_in, const int* in_sizes, int n_in,
                              void* d_out, int out_size, void* d_ws, size_t ws_size,
                              hipStream_t stream) {
    const float* x = (const float*)d_in[0];   // [32, 8192, 128, 1] fp32
    const float* w = (const float*)d_in[1];   // [7, 128, 128] fp32
    float* out = (float*)d_out;               // [32, 8186, 128, 1] fp32
    ushort* wt = (ushort*)d_ws;               // 7*128*128 bf16 = 229,376 B scratch

    wconv_kernel<<<448, 256, 0, stream>>>(w, wt);
    conv_gemm_kernel<<<BATCH * 64, 256, 0, stream>>>(x, wt, out);
}

// Round 5
// 261.630 us; speedup vs baseline: 1.0457x; 1.0132x over previous
//
#include <hip/hip_runtime.h>
#include <hip/hip_bf16.h>

// Problem constants (from reference): B=32, L=8192, C=128, K=7, F=128
#define BATCH 32
#define LEN   8192
#define CDIM  128
#define TAPS  7
#define FDIM  128
#define LOUT  (LEN - TAPS + 1)   // 8186
#define BM    128                // output rows per block
#define XROWS (BM + TAPS - 1)    // 134 rows of x per block
#define NIT   (TAPS * 2 * 4)     // 56 flattened (tap, C-half, kk) steps

typedef __attribute__((ext_vector_type(8)))  short bf16x8;
typedef __attribute__((ext_vector_type(16))) float f32x16;

static __device__ __forceinline__ unsigned short bf16_rne(float f) {
    unsigned u = __float_as_uint(f);
    u += 0x7FFFu + ((u >> 16) & 1u);
    return (unsigned short)(u >> 16);
}
static __device__ __forceinline__ unsigned pack2(float a, float b) {
    return (unsigned)bf16_rne(a) | ((unsigned)bf16_rne(b) << 16);
}

// Pre-convert W fp32 [K][C][F] -> bf16 in MFMA-FRAGMENT-MAJOR order:
// wt[t][h][kk][l5][f][e], e=0..7, where c = h*64 + kk*16 + l5*8 + e.
// Step s = t*8 + h*4 + kk lives at ushort offset s*2048: a B-fragment load
// is a perfectly coalesced contiguous 512 B per 32-lane half.
__global__ void wconv_kernel(const float* __restrict__ w, ushort* __restrict__ wt) {
    int i = blockIdx.x * 256 + threadIdx.x;   // 7*2*4*2*128*8 = 114688 = 448*256
    int e  = i & 7;
    int f  = (i >> 3) & 127;
    int l5 = (i >> 10) & 1;
    int kk = (i >> 11) & 3;
    int h  = (i >> 13) & 1;
    int t  = i >> 14;
    int c  = h * 64 + kk * 16 + l5 * 8 + e;
    wt[i] = bf16_rne(w[(t << 14) + (c << 7) + f]);
}

// Main fused conv-as-GEMM kernel (round-2 structure, benched 110 us).
// NEW this round: per-block ROTATED step order. Round-2 analysis: per-step
// exposed stall = ~2360 cyc, ~6x any single-load latency. All blocks sweep
// the SAME 3,584 W cache lines in lockstep -> at any instant the whole XCD
// requests the same ~64 lines -> L2 same-line/bank serialization (effective
// ~5 lines/cyc/XCD vs ~67 ubench) is the theorized wall. Starting each
// block's sweep at (bid % 56) makes concurrent blocks request DISJOINT
// 2 KB W chunks -> requests spread across all lines/banks. Accumulation
// order change only (fp32 acc) -> bitwise-tolerant. Waves within a block
// stay on the same step (preserves L1 sharing of wm-duplicate W reads).
__global__ __launch_bounds__(256, 4)
void conv_gemm_kernel(const float* __restrict__ x, const ushort* __restrict__ wt,
                      float* __restrict__ out) {
    __shared__ __align__(16) ushort Xs[XROWS * CDIM];      // 34,304 B (X only)

    const int tid  = threadIdx.x;
    const int lane = tid & 63;
    const int wid  = tid >> 6;       // 0..3
    const int wm   = wid >> 1;       // wave row (0..1) -> 64 rows
    const int wn   = wid & 1;        // wave col (0..1) -> 64 f
    const int l31  = lane & 31;
    const int l5   = lane >> 5;

    const int bid  = blockIdx.x;
    const int b    = bid >> 6;       // 64 row-tiles per batch
    const int i0   = (bid & 63) * BM;
    const int it0  = bid % NIT;      // per-block sweep rotation

    const float* xb = x + (size_t)b * LEN * CDIM;

    // ---- Stage X window: fp32 global -> bf16 LDS, swizzled (col ^= row&15) ----
    #pragma unroll
    for (int it = 0; it < 9; ++it) {
        int q = it * 256 + tid;
        if (q < XROWS * 16) {
            int r   = q >> 4;
            int col = q & 15;
            int gi  = i0 + r;
            float4 v0, v1;
            if (gi < LEN) {
                const float4* p = (const float4*)(xb + (size_t)gi * CDIM + col * 8);
                v0 = p[0]; v1 = p[1];
            } else {
                v0 = make_float4(0.f, 0.f, 0.f, 0.f);
                v1 = v0;
            }
            int scol = col ^ (r & 15);
            uint4 pk;
            pk.x = pack2(v0.x, v0.y);
            pk.y = pack2(v0.z, v0.w);
            pk.z = pack2(v1.x, v1.y);
            pk.w = pack2(v1.z, v1.w);
            *(uint4*)&Xs[r * CDIM + scol * 8] = pk;
        }
    }
    __syncthreads();                 // the ONLY barrier

    f32x16 acc[2][2] = {};

    const int f0 = (wn << 6) + l31;
    const int rb = (wm << 6) + l31;  // fragment row base (+t per tap)

    // Per-lane W fragment base; step s lives at ushort offset s*2048.
    const ushort* wlp = wt + (l5 << 10) + (f0 << 3);

    #pragma unroll
    for (int it = 0; it < NIT; ++it) {
        int s = it + it0;
        if (s >= NIT) s -= NIT;      // rotated step index

        const int t  = s >> 3;           // tap
        const int h  = (s >> 2) & 1;     // C-half
        const int kk = s & 3;
        const int jl = kk * 2 + l5;      // 0..7 within the C-half
        const int jg = h * 8 + jl;       // 0..15 within the full row (for Xs)
        const int r0 = rb + t;
        const int r1 = r0 + 32;
        const ushort* wpi = wlp + s * 2048;

        bf16x8 a0 = *(const bf16x8*)&Xs[r0 * CDIM + ((jg ^ (r0 & 15)) << 3)];
        bf16x8 a1 = *(const bf16x8*)&Xs[r1 * CDIM + ((jg ^ (r1 & 15)) << 3)];
        bf16x8 b0 = *(const bf16x8*)(wpi);
        bf16x8 b1 = *(const bf16x8*)(wpi + 256);   // f0 + 32

        acc[0][0] = __builtin_amdgcn_mfma_f32_32x32x16_bf16(a0, b0, acc[0][0], 0, 0, 0);
        acc[0][1] = __builtin_amdgcn_mfma_f32_32x32x16_bf16(a0, b1, acc[0][1], 0, 0, 0);
        acc[1][0] = __builtin_amdgcn_mfma_f32_32x32x16_bf16(a1, b0, acc[1][0], 0, 0, 0);
        acc[1][1] = __builtin_amdgcn_mfma_f32_32x32x16_bf16(a1, b1, acc[1][1], 0, 0, 0);
    }

    // ---- Epilogue: C/D layout col=lane&31, row=(reg&3)+8*(reg>>2)+4*(lane>>5) ----
    float* ob = out + (size_t)b * LOUT * FDIM;
    #pragma unroll
    for (int fm = 0; fm < 2; ++fm) {
        #pragma unroll
        for (int fn = 0; fn < 2; ++fn) {
            #pragma unroll
            for (int r = 0; r < 16; ++r) {
                int row = (wm << 6) + (fm << 5) + (r & 3) + ((r >> 2) << 3) + (l5 << 2);
                int i = i0 + row;
                if (i < LOUT) {
                    ob[(size_t)i * FDIM + (wn << 6) + (fn << 5) + l31] = acc[fm][fn][r];
                }
            }
        }
    }
}

extern "C" void kernel_launch(void* const* d_in, const int* in_sizes, int n_in,
                              void* d_out, int out_size, void* d_ws, size_t ws_size,
                              hipStream_t stream) {
    const float* x = (const float*)d_in[0];   // [32, 8192, 128, 1] fp32
    const float* w = (const float*)d_in[1];   // [7, 128, 128] fp32
    float* out = (float*)d_out;               // [32, 8186, 128, 1] fp32
    ushort* wt = (ushort*)d_ws;               // 7*128*128 bf16 = 229,376 B scratch

    wconv_kernel<<<448, 256, 0, stream>>>(w, wt);
    conv_gemm_kernel<<<BATCH * 64, 256, 0, stream>>>(x, wt, out);
}